// Round 4
// baseline (1180.868 us; speedup 1.0000x reference)
//
#include <hip/hip_runtime.h>

// GCNStoModel_MultiHead: 2-layer GraphSAGE-GCN + linear head.
// IN=128, HID=256, OUT=256, PHEAD=64
// N0=1048576, E0=2097152, ND0=131072, E1=131072, ND1=8192, task_index=0.
//
// R1: CSR build + gather aggregation (no float atomics).
// R2: agg latency fix — cooperative edge-index load + __shfl broadcast +
//     8-deep software-pipelined gathers.
// R3: dead-row elimination (needed-mask; only ~66% of ND0 rows consumed).
// R4 (REVERTED): agg0+gemm1 fusion killed gather occupancy (8 waves/CU vs 32)
//     -> gather ran at 1.4 TB/s. Lesson: the gather needs wave count.
// R5: keep R3's high-occupancy agg + compaction; (a) fuse 20 dispatches into
//     11 (mark+hist0+hist1 one launch; 3 block-sums one; 3 small-scans one;
//     3 final-scans one; fill0+fill1 one); (b) drop needed-check from
//     hist0/fill0 (unneeded rows get CSR entries nobody reads); (c) gemm1 as
//     a 64x256-wide tile reading the A panel ONCE (was 4 column-block
//     re-reads), same k-order -> bitwise-identical h1.

#define GEMM_BM 64
#define GEMM_BN 64
#define GEMM_BK 32

// ---------------------------------------------------------------------------
// fused launch 2: blocks [0,E0/256) hist0; [E0/256, +E1/256) hist1;
// [.., +E1/256) mark. All independent; arrays pre-zeroed.
__global__ __launch_bounds__(256) void mark_hist_kernel(const int* __restrict__ dst0,
                                                        int* __restrict__ count0, int E0,
                                                        const int* __restrict__ dst1,
                                                        int* __restrict__ count1, int E1,
                                                        const int* __restrict__ src1,
                                                        int* __restrict__ needed, int nd1) {
    const int b = blockIdx.x;
    const int nb0 = E0 / 256, nb1 = E1 / 256;
    const int t = threadIdx.x;
    if (b < nb0) {
        int e = b * 256 + t;
        atomicAdd(&count0[dst0[e]], 1);
    } else if (b < nb0 + nb1) {
        int e = (b - nb0) * 256 + t;
        atomicAdd(&count1[dst1[e]], 1);
    } else {
        int e = (b - nb0 - nb1) * 256 + t;
        if (e < nd1) needed[e] = 1;
        needed[src1[e]] = 1;
    }
}

// ---------------------------------------------------------------------------
__device__ __forceinline__ void dev_block_sum(const int* __restrict__ in,
                                              int* __restrict__ bsum, int lb) {
    __shared__ int sdata[256];
    int t = threadIdx.x;
    int i = lb * 1024 + t * 4;
    int s = in[i] + in[i + 1] + in[i + 2] + in[i + 3];
    sdata[t] = s;
    __syncthreads();
    for (int off = 128; off > 0; off >>= 1) {
        if (t < off) sdata[t] += sdata[t + off];
        __syncthreads();
    }
    if (t == 0) bsum[lb] = sdata[0];
}

// fused launch 3: block sums for needed (128), count0 (128), count1 (8)
__global__ __launch_bounds__(256) void bsum3_kernel(const int* __restrict__ needed,
                                                    int* __restrict__ bsumA,
                                                    const int* __restrict__ count0,
                                                    int* __restrict__ bsumB,
                                                    const int* __restrict__ count1,
                                                    int* __restrict__ bsumC,
                                                    int nbA, int nbB) {
    const int b = blockIdx.x;
    if (b < nbA)            dev_block_sum(needed, bsumA, b);
    else if (b < nbA + nbB) dev_block_sum(count0, bsumB, b - nbA);
    else                    dev_block_sum(count1, bsumC, b - nbA - nbB);
}

// ---------------------------------------------------------------------------
__device__ __forceinline__ void dev_scan_small(const int* __restrict__ bsum,
                                               int* __restrict__ boff, int nb,
                                               int* __restrict__ total) {
    __shared__ int sdata[256];
    int t = threadIdx.x;
    int v = (t < nb) ? bsum[t] : 0;
    sdata[t] = v;
    __syncthreads();
    int val = v;
    for (int off = 1; off < 256; off <<= 1) {
        int x = (t >= off) ? sdata[t - off] : 0;
        __syncthreads();
        val += x;
        sdata[t] = val;
        __syncthreads();
    }
    if (t < nb) boff[t] = val - v;  // exclusive
    if (total != nullptr && t == nb - 1) *total = val;
}

// fused launch 4: the three tiny scans (3 blocks)
__global__ __launch_bounds__(256) void scan3_kernel(const int* __restrict__ bsumA,
                                                    int* __restrict__ boffA, int nbA,
                                                    int* __restrict__ nr_ptr,
                                                    const int* __restrict__ bsumB,
                                                    int* __restrict__ boffB, int nbB,
                                                    const int* __restrict__ bsumC,
                                                    int* __restrict__ boffC, int nbC) {
    if (blockIdx.x == 0)      dev_scan_small(bsumA, boffA, nbA, nr_ptr);
    else if (blockIdx.x == 1) dev_scan_small(bsumB, boffB, nbB, nullptr);
    else                      dev_scan_small(bsumC, boffC, nbC, nullptr);
}

// ---------------------------------------------------------------------------
__device__ __forceinline__ void dev_scan_final(const int* __restrict__ in,
                                               const int* __restrict__ boff,
                                               int* __restrict__ out1,
                                               int* __restrict__ out2, int lb) {
    __shared__ int sdata[256];
    int t = threadIdx.x;
    int base_i = lb * 1024 + t * 4;
    int c0 = in[base_i], c1 = in[base_i + 1], c2 = in[base_i + 2], c3 = in[base_i + 3];
    int local = c0 + c1 + c2 + c3;
    sdata[t] = local;
    __syncthreads();
    int val = local;
    for (int off = 1; off < 256; off <<= 1) {
        int x = (t >= off) ? sdata[t - off] : 0;
        __syncthreads();
        val += x;
        sdata[t] = val;
        __syncthreads();
    }
    int base = boff[lb] + (val - local);  // exclusive prefix
    int r0 = base, r1 = r0 + c0, r2 = r1 + c1, r3 = r2 + c2;
    out1[base_i] = r0; out1[base_i + 1] = r1;
    out1[base_i + 2] = r2; out1[base_i + 3] = r3;
    out2[base_i] = r0; out2[base_i + 1] = r1;
    out2[base_i + 2] = r2; out2[base_i + 3] = r3;
}

// fused launch 5: rank-final (needed->rank), csr0-final, csr1-final
__global__ __launch_bounds__(256) void final3_kernel(const int* __restrict__ needed,
                                                     const int* __restrict__ boffA,
                                                     int* __restrict__ rank,
                                                     const int* __restrict__ count0,
                                                     const int* __restrict__ boffB,
                                                     int* __restrict__ row_start0,
                                                     int* __restrict__ cursor0,
                                                     const int* __restrict__ count1,
                                                     const int* __restrict__ boffC,
                                                     int* __restrict__ row_start1,
                                                     int* __restrict__ cursor1,
                                                     int nbA, int nbB) {
    const int b = blockIdx.x;
    if (b < nbA)            dev_scan_final(needed, boffA, rank, rank, b);
    else if (b < nbA + nbB) dev_scan_final(count0, boffB, row_start0, cursor0, b - nbA);
    else                    dev_scan_final(count1, boffC, row_start1, cursor1, b - nbA - nbB);
}

// ---------------------------------------------------------------------------
// fused launch 6: fill0 (no remap) + fill1 (remap src -> rank)
__global__ __launch_bounds__(256) void fill2_kernel(const int* __restrict__ src0,
                                                    const int* __restrict__ dst0,
                                                    int* __restrict__ cursor0,
                                                    int* __restrict__ edge_src0, int E0,
                                                    const int* __restrict__ src1,
                                                    const int* __restrict__ dst1,
                                                    const int* __restrict__ rank,
                                                    int* __restrict__ cursor1,
                                                    int* __restrict__ edge_src1, int E1) {
    const int b = blockIdx.x;
    const int nb0 = E0 / 256;
    const int t = threadIdx.x;
    if (b < nb0) {
        int e = b * 256 + t;
        int d = dst0[e];
        int p = atomicAdd(&cursor0[d], 1);
        edge_src0[p] = src0[e];
    } else {
        int e = (b - nb0) * 256 + t;
        int d = dst1[e];
        int p = atomicAdd(&cursor1[d], 1);
        edge_src1[p] = rank[src1[e]];
    }
}

// ---------------------------------------------------------------------------
// gather aggregation: one wave per dst row; row held in registers (RF floats
// per lane, K = 64*RF). COMPACT: skip rows with needed==0, write at rank[w].
template<int RF> struct VecSel;
template<> struct VecSel<2> { using V = float2; };
template<> struct VecSel<4> { using V = float4; };

template<int RF, bool COMPACT>
__global__ __launch_bounds__(256) void agg_kernel(const float* __restrict__ feat,
                                                  const float* __restrict__ selff,
                                                  const int* __restrict__ row_start,
                                                  const int* __restrict__ count,
                                                  const int* __restrict__ edge_src,
                                                  const int* __restrict__ needed,
                                                  const int* __restrict__ rank,
                                                  float* __restrict__ neigh,
                                                  float* __restrict__ deg, int ND) {
    using V = typename VecSel<RF>::V;
    int w = (blockIdx.x * 256 + threadIdx.x) >> 6;  // wave id == dst row
    int lane = threadIdx.x & 63;
    if (w >= ND) return;
    int out_r = w;
    if constexpr (COMPACT) {
        if (needed[w] == 0) return;
        out_r = rank[w];
    }
    const int K = 64 * RF;
    size_t lo_in  = (size_t)w * K + (size_t)lane * RF;
    size_t lo_out = (size_t)out_r * K + (size_t)lane * RF;
    V acc = *(const V*)(selff + lo_in);
    const int rs = row_start[w];
    const int cnt = count[w];

    for (int base = 0; base < cnt; base += 64) {
        const int rem = min(cnt - base, 64);
        const int idx = edge_src[rs + base + min(lane, rem - 1)];
        for (int jj = 0; jj < rem; jj += 8) {
            int s[8];
            float m[8];
            #pragma unroll
            for (int k = 0; k < 8; ++k) {
                int j = jj + k;
                s[k] = __shfl(idx, min(j, rem - 1));
                m[k] = (j < rem) ? 1.0f : 0.0f;
            }
            V v[8];
            #pragma unroll
            for (int k = 0; k < 8; ++k)
                v[k] = *(const V*)(feat + (size_t)s[k] * K + (size_t)lane * RF);
            #pragma unroll
            for (int k = 0; k < 8; ++k) {
                acc.x += v[k].x * m[k];
                acc.y += v[k].y * m[k];
                if constexpr (RF == 4) {
                    acc.z += v[k].z * m[k];
                    acc.w += v[k].w * m[k];
                }
            }
        }
    }
    *(V*)(neigh + lo_out) = acc;
    if (lane == 0) deg[out_r] = (float)(cnt + 1);
}

// ---------------------------------------------------------------------------
// gemm1 wide: C[64][256] = relu( (A[64][128] * 1/deg) @ W^T + b ).
// A panel staged ONCE per block (no column-block re-reads); W in 32-k LDS
// chunks from L2. Dynamic M (*nr_ptr); pad rows compute garbage, never read.
// Same k-summation order as the 64x64 kernel -> bitwise-identical output.
__global__ __launch_bounds__(256) void gemm1_wide_kernel(const float* __restrict__ A,    // [ND0][128]
                                                         const float* __restrict__ deg,  // [>=M]
                                                         const float* __restrict__ W,    // [256][128]
                                                         const float* __restrict__ bias, // [256]
                                                         float* __restrict__ C,          // [ND0][256]
                                                         const int* __restrict__ nr_ptr) {
    __shared__ float rows[64][129];   // [m][k]
    __shared__ float Ws[32][256];     // [k][n]

    const int nr = *nr_ptr;
    const int row0 = blockIdx.x * 64;
    if (row0 >= nr) return;           // uniform; before any __syncthreads

    const int t = threadIdx.x;

    // stage A panel: thread t loads row lr = t>>2, cols (t&3)*32 .. +31
    {
        const int lr = t >> 2;
        const int lc = (t & 3) * 32;
        const float* srcp = A + (size_t)(row0 + lr) * 128 + lc;
        #pragma unroll
        for (int j = 0; j < 8; ++j) {
            float4 v = *(const float4*)(srcp + j * 4);
            rows[lr][lc + j * 4 + 0] = v.x; rows[lr][lc + j * 4 + 1] = v.y;
            rows[lr][lc + j * 4 + 2] = v.z; rows[lr][lc + j * 4 + 3] = v.w;
        }
    }
    __syncthreads();

    const int tm = (t & 15) * 4;
    const int tn = (t >> 4) * 16;
    float acc[4][16] = {};

    for (int kc = 0; kc < 128; kc += 32) {
        // stage Ws[k][n] = W[n][kc+k]; thread t owns column n = t
        {
            const float* srcp = W + (size_t)t * 128 + kc;
            #pragma unroll
            for (int j = 0; j < 8; ++j) {
                float4 v = *(const float4*)(srcp + j * 4);
                Ws[j * 4 + 0][t] = v.x; Ws[j * 4 + 1][t] = v.y;
                Ws[j * 4 + 2][t] = v.z; Ws[j * 4 + 3][t] = v.w;
            }
        }
        __syncthreads();
        #pragma unroll 8
        for (int k = 0; k < 32; ++k) {
            const int kk = kc + k;
            float a0 = rows[tm + 0][kk];
            float a1 = rows[tm + 1][kk];
            float a2 = rows[tm + 2][kk];
            float a3 = rows[tm + 3][kk];
            #pragma unroll
            for (int q = 0; q < 4; ++q) {
                const float4 wv4 = *(const float4*)&Ws[k][tn + q * 4];
                acc[0][q * 4 + 0] += a0 * wv4.x; acc[0][q * 4 + 1] += a0 * wv4.y;
                acc[0][q * 4 + 2] += a0 * wv4.z; acc[0][q * 4 + 3] += a0 * wv4.w;
                acc[1][q * 4 + 0] += a1 * wv4.x; acc[1][q * 4 + 1] += a1 * wv4.y;
                acc[1][q * 4 + 2] += a1 * wv4.z; acc[1][q * 4 + 3] += a1 * wv4.w;
                acc[2][q * 4 + 0] += a2 * wv4.x; acc[2][q * 4 + 1] += a2 * wv4.y;
                acc[2][q * 4 + 2] += a2 * wv4.z; acc[2][q * 4 + 3] += a2 * wv4.w;
                acc[3][q * 4 + 0] += a3 * wv4.x; acc[3][q * 4 + 1] += a3 * wv4.y;
                acc[3][q * 4 + 2] += a3 * wv4.z; acc[3][q * 4 + 3] += a3 * wv4.w;
            }
        }
        __syncthreads();
    }

    float bb[16];
    #pragma unroll
    for (int q = 0; q < 4; ++q) {
        const float4 b4 = *(const float4*)(bias + tn + q * 4);
        bb[q * 4 + 0] = b4.x; bb[q * 4 + 1] = b4.y;
        bb[q * 4 + 2] = b4.z; bb[q * 4 + 3] = b4.w;
    }
    #pragma unroll
    for (int i = 0; i < 4; ++i) {
        const float scl = 1.0f / deg[row0 + tm + i];
        float* dstp = C + (size_t)(row0 + tm + i) * 256 + tn;
        #pragma unroll
        for (int q = 0; q < 4; ++q) {
            float4 r;
            r.x = fmaxf(acc[i][q * 4 + 0] * scl + bb[q * 4 + 0], 0.0f);
            r.y = fmaxf(acc[i][q * 4 + 1] * scl + bb[q * 4 + 1], 0.0f);
            r.z = fmaxf(acc[i][q * 4 + 2] * scl + bb[q * 4 + 2], 0.0f);
            r.w = fmaxf(acc[i][q * 4 + 3] * scl + bb[q * 4 + 3], 0.0f);
            *(float4*)(dstp + q * 4) = r;
        }
    }
}

// ---------------------------------------------------------------------------
// C[M,N] = act( (A * rowscale) @ W^T + b ), fp32, 64x64x32 tiles, 4x4/thread.
template<bool RELU, bool HAS_RS>
__global__ __launch_bounds__(256) void gemm_kernel(const float* __restrict__ A,    // M x K
                                                   const float* __restrict__ deg,  // M or null
                                                   const float* __restrict__ W,    // N x K
                                                   const float* __restrict__ bias, // N
                                                   float* __restrict__ C,          // M x N
                                                   int N, int K) {
    __shared__ float As[GEMM_BK][GEMM_BM];  // [k][m]
    __shared__ float Ws[GEMM_BK][GEMM_BN];  // [k][n]

    const int t = threadIdx.x;
    const int row0 = blockIdx.x * GEMM_BM;
    const int col0 = blockIdx.y * GEMM_BN;

    const int tm = (t & 15) * 4;
    const int tn = (t >> 4) * 4;

    float acc[4][4] = {};

    const int lr = t >> 3;       // 0..31
    const int lk = (t & 7) * 4;  // 0,4,...,28

    for (int k0 = 0; k0 < K; k0 += GEMM_BK) {
        #pragma unroll
        for (int pass = 0; pass < 2; ++pass) {
            int r = lr + pass * 32;
            const float4 v = *(const float4*)(A + (size_t)(row0 + r) * K + k0 + lk);
            As[lk + 0][r] = v.x; As[lk + 1][r] = v.y;
            As[lk + 2][r] = v.z; As[lk + 3][r] = v.w;
        }
        #pragma unroll
        for (int pass = 0; pass < 2; ++pass) {
            int n = lr + pass * 32;
            const float4 v = *(const float4*)(W + (size_t)(col0 + n) * K + k0 + lk);
            Ws[lk + 0][n] = v.x; Ws[lk + 1][n] = v.y;
            Ws[lk + 2][n] = v.z; Ws[lk + 3][n] = v.w;
        }
        __syncthreads();

        #pragma unroll
        for (int k = 0; k < GEMM_BK; ++k) {
            const float4 a = *(const float4*)&As[k][tm];
            const float4 w = *(const float4*)&Ws[k][tn];
            acc[0][0] += a.x * w.x; acc[0][1] += a.x * w.y; acc[0][2] += a.x * w.z; acc[0][3] += a.x * w.w;
            acc[1][0] += a.y * w.x; acc[1][1] += a.y * w.y; acc[1][2] += a.y * w.z; acc[1][3] += a.y * w.w;
            acc[2][0] += a.z * w.x; acc[2][1] += a.z * w.y; acc[2][2] += a.z * w.z; acc[2][3] += a.z * w.w;
            acc[3][0] += a.w * w.x; acc[3][1] += a.w * w.y; acc[3][2] += a.w * w.z; acc[3][3] += a.w * w.w;
        }
        __syncthreads();
    }

    float scl[4];
    #pragma unroll
    for (int i = 0; i < 4; ++i)
        scl[i] = HAS_RS ? (1.0f / deg[row0 + tm + i]) : 1.0f;

    float bb[4];
    #pragma unroll
    for (int j = 0; j < 4; ++j) bb[j] = bias[col0 + tn + j];

    #pragma unroll
    for (int i = 0; i < 4; ++i) {
        float4 v;
        v.x = acc[i][0] * scl[i] + bb[0];
        v.y = acc[i][1] * scl[i] + bb[1];
        v.z = acc[i][2] * scl[i] + bb[2];
        v.w = acc[i][3] * scl[i] + bb[3];
        if (RELU) {
            v.x = fmaxf(v.x, 0.0f); v.y = fmaxf(v.y, 0.0f);
            v.z = fmaxf(v.z, 0.0f); v.w = fmaxf(v.w, 0.0f);
        }
        *(float4*)(C + (size_t)(row0 + tm + i) * N + col0 + tn) = v;
    }
}

// ---------------------------------------------------------------------------
extern "C" void kernel_launch(void* const* d_in, const int* in_sizes, int n_in,
                              void* d_out, int out_size, void* d_ws, size_t ws_size,
                              hipStream_t stream) {
    const float* x   = (const float*)d_in[0];
    const int* src0  = (const int*)d_in[1];
    const int* dst0  = (const int*)d_in[2];
    const int* src1  = (const int*)d_in[3];
    const int* dst1  = (const int*)d_in[4];
    const float* W1  = (const float*)d_in[5];
    const float* b1  = (const float*)d_in[6];
    const float* W2  = (const float*)d_in[7];
    const float* b2  = (const float*)d_in[8];
    const float* Wh  = (const float*)d_in[9];
    const float* bh  = (const float*)d_in[10];

    const int E0 = in_sizes[1];
    const int E1 = in_sizes[3];
    const int IN = 128, HID = 256, OUT = 256, PHEAD = 64;
    const int ND0 = 131072, ND1 = 8192;

    // ---- workspace layout (non-overlapping) ----
    float* ws = (float*)d_ws;
    float* neigh0c = ws;                               // ND0*IN  (worst case)
    float* deg0c   = neigh0c + (size_t)ND0 * IN;       // ND0
    float* h1c     = deg0c + ND0;                      // ND0*HID (worst case)
    float* neigh1  = h1c + (size_t)ND0 * HID;          // ND1*HID
    float* deg1    = neigh1 + (size_t)ND1 * HID;       // ND1
    float* h2      = deg1 + ND1;                       // ND1*OUT
    float* out     = (float*)d_out;                    // ND1*PHEAD

    // count0, needed, count1 contiguous -> zeroed in ONE memset
    int* count0     = (int*)(h2 + (size_t)ND1 * OUT);  // ND0
    int* needed     = count0 + ND0;                    // ND0
    int* count1     = needed + ND0;                    // ND1
    int* rank       = count1 + ND1;                    // ND0
    int* row_start0 = rank + ND0;                      // ND0
    int* cursor0    = row_start0 + ND0;                // ND0
    int* edge_src0  = cursor0 + ND0;                   // E0
    int* row_start1 = edge_src0 + E0;                  // ND1
    int* cursor1    = row_start1 + ND1;                // ND1
    int* edge_src1  = cursor1 + ND1;                   // E1
    int* bsumA      = edge_src1 + E1;                  // 256
    int* boffA      = bsumA + 256;                     // 256
    int* bsumB      = boffA + 256;                     // 256
    int* boffB      = bsumB + 256;                     // 256
    int* bsumC      = boffB + 256;                     // 256
    int* boffC      = bsumC + 256;                     // 256
    int* nr_ptr     = boffC + 256;                     // 1: needed row count

    const int nbA = ND0 / 1024;  // 128 (needed scan)
    const int nbB = ND0 / 1024;  // 128 (count0 scan)
    const int nbC = ND1 / 1024;  // 8   (count1 scan)

    // 1. zero count0 + needed + count1
    hipMemsetAsync(count0, 0, (size_t)(2 * ND0 + ND1) * sizeof(int), stream);

    // 2. hist0 (full E0) + hist1 + mark, one launch
    mark_hist_kernel<<<E0 / 256 + 2 * (E1 / 256), 256, 0, stream>>>(
        dst0, count0, E0, dst1, count1, E1, src1, needed, ND1);

    // 3. three block-sum passes, one launch
    bsum3_kernel<<<nbA + nbB + nbC, 256, 0, stream>>>(needed, bsumA, count0, bsumB,
                                                      count1, bsumC, nbA, nbB);

    // 4. three small scans, one launch (3 blocks)
    scan3_kernel<<<3, 256, 0, stream>>>(bsumA, boffA, nbA, nr_ptr,
                                        bsumB, boffB, nbB, bsumC, boffC, nbC);

    // 5. three final scans (rank, csr0, csr1), one launch
    final3_kernel<<<nbA + nbB + nbC, 256, 0, stream>>>(
        needed, boffA, rank, count0, boffB, row_start0, cursor0,
        count1, boffC, row_start1, cursor1, nbA, nbB);

    // 6. fill0 + fill1 (remapped to ranks), one launch
    fill2_kernel<<<E0 / 256 + E1 / 256, 256, 0, stream>>>(
        src0, dst0, cursor0, edge_src0, E0,
        src1, dst1, rank, cursor1, edge_src1, E1);

    // 7. layer-0 gather aggregate (compacted out)
    agg_kernel<2, true><<<ND0 / 4, 256, 0, stream>>>(x, x, row_start0, count0, edge_src0,
                                                     needed, rank, neigh0c, deg0c, ND0);

    // 8. gemm1: wide 64x256 tile, dynamic M
    gemm1_wide_kernel<<<ND0 / 64, 256, 0, stream>>>(neigh0c, deg0c, W1, b1, h1c, nr_ptr);

    // 9. layer-1 gather aggregate (edges pre-remapped; rank[d]=d for d<ND1)
    agg_kernel<4, false><<<ND1 / 4, 256, 0, stream>>>(h1c, h1c, row_start1, count1, edge_src1,
                                                      nullptr, nullptr, neigh1, deg1, ND1);

    // 10. gemm2
    {
        dim3 g(ND1 / GEMM_BM, OUT / GEMM_BN);
        gemm_kernel<true, true><<<g, 256, 0, stream>>>(neigh1, deg1, W2, b2, h2, OUT, HID);
    }

    // 11. head
    {
        dim3 g(ND1 / GEMM_BM, PHEAD / GEMM_BN);
        gemm_kernel<false, false><<<g, 256, 0, stream>>>(h2, nullptr, Wh, bh, out, PHEAD, OUT);
    }
}

// Round 5
// 1039.011 us; speedup vs baseline: 1.1365x; 1.1365x over previous
//
#include <hip/hip_runtime.h>

// GCNStoModel_MultiHead: 2-layer GraphSAGE-GCN + linear head.
// IN=128, HID=256, OUT=256, PHEAD=64
// N0=1048576, E0=2097152, ND0=131072, E1=131072, ND1=8192, task_index=0.
//
// R1: CSR build + gather aggregation (no float atomics).
// R2: agg latency fix — cooperative edge-index load + __shfl broadcast +
//     8-deep software-pipelined gathers.
// R3: dead-row elimination (needed-mask; only ~66% of ND0 rows consumed). 1058us.
// R4 (REVERTED): agg0+gemm1 fusion killed gather occupancy -> 1.4 TB/s gather.
// R5 (REVERTED): bundled {fusion, uncheck hist0/fill0, wide gemm1} -> 1181us.
//     Can't attribute; unbundle.
// R6: R3 kernel bodies VERBATIM; ONLY dependency-safe launch fusion
//     (20 -> 13 dispatches). Segments within a launch are independent and
//     their inputs were produced by earlier launches, so all math/memory
//     behavior per kernel is identical to R3.

#define GEMM_BM 64
#define GEMM_BN 64
#define GEMM_BK 32

// ---------------------------------------------------------------------------
// device helpers (bodies identical to R3's kernels)
__device__ __forceinline__ void dev_block_sum(const int* __restrict__ in,
                                              int* __restrict__ bsum, int lb) {
    __shared__ int sdata[256];
    int t = threadIdx.x;
    int i = lb * 1024 + t * 4;
    int s = in[i] + in[i + 1] + in[i + 2] + in[i + 3];
    sdata[t] = s;
    __syncthreads();
    for (int off = 128; off > 0; off >>= 1) {
        if (t < off) sdata[t] += sdata[t + off];
        __syncthreads();
    }
    if (t == 0) bsum[lb] = sdata[0];
}

__device__ __forceinline__ void dev_scan_small(const int* __restrict__ bsum,
                                               int* __restrict__ boff, int nb,
                                               int* __restrict__ total) {
    __shared__ int sdata[256];
    int t = threadIdx.x;
    int v = (t < nb) ? bsum[t] : 0;
    sdata[t] = v;
    __syncthreads();
    int val = v;
    for (int off = 1; off < 256; off <<= 1) {
        int x = (t >= off) ? sdata[t - off] : 0;
        __syncthreads();
        val += x;
        sdata[t] = val;
        __syncthreads();
    }
    if (t < nb) boff[t] = val - v;  // exclusive
    if (total != nullptr && t == nb - 1) *total = val;
}

__device__ __forceinline__ void dev_scan_final(const int* __restrict__ in,
                                               const int* __restrict__ boff,
                                               int* __restrict__ out1,
                                               int* __restrict__ out2, int lb) {
    __shared__ int sdata[256];
    int t = threadIdx.x;
    int base_i = lb * 1024 + t * 4;
    int c0 = in[base_i], c1 = in[base_i + 1], c2 = in[base_i + 2], c3 = in[base_i + 3];
    int local = c0 + c1 + c2 + c3;
    sdata[t] = local;
    __syncthreads();
    int val = local;
    for (int off = 1; off < 256; off <<= 1) {
        int x = (t >= off) ? sdata[t - off] : 0;
        __syncthreads();
        val += x;
        sdata[t] = val;
        __syncthreads();
    }
    int base = boff[lb] + (val - local);  // exclusive prefix
    int r0 = base, r1 = r0 + c0, r2 = r1 + c1, r3 = r2 + c2;
    out1[base_i] = r0; out1[base_i + 1] = r1;
    out1[base_i + 2] = r2; out1[base_i + 3] = r3;
    out2[base_i] = r0; out2[base_i + 1] = r1;
    out2[base_i + 2] = r2; out2[base_i + 3] = r3;
}

// ---------------------------------------------------------------------------
// launch 2: mark (needs zeroed `needed`) + hist1 (needs zeroed count1)
__global__ __launch_bounds__(256) void mark_hist1_kernel(const int* __restrict__ src1,
                                                         int* __restrict__ needed, int nd1,
                                                         const int* __restrict__ dst1,
                                                         int* __restrict__ count1, int E1) {
    const int b = blockIdx.x;
    const int nb1 = E1 / 256;
    const int t = threadIdx.x;
    if (b < nb1) {                       // hist1
        int e = b * 256 + t;
        atomicAdd(&count1[dst1[e]], 1);
    } else {                             // mark
        int e = (b - nb1) * 256 + t;
        if (e < nd1) needed[e] = 1;
        needed[src1[e]] = 1;
    }
}

// launch 3: hist0 (needed-checked; needs mark) + bsumA(needed) + bsumC(count1)
__global__ __launch_bounds__(256) void hist0_bsumAC_kernel(const int* __restrict__ dst0,
                                                           const int* __restrict__ needed,
                                                           int* __restrict__ count0, int E0,
                                                           int* __restrict__ bsumA, int nbA,
                                                           const int* __restrict__ count1,
                                                           int* __restrict__ bsumC) {
    const int b = blockIdx.x;
    const int nb0 = E0 / 256;
    if (b < nb0) {                       // hist0 (identical to R3 hist_kernel)
        int e = b * 256 + threadIdx.x;
        int d = dst0[e];
        if (needed[d] == 0) return;
        atomicAdd(&count0[d], 1);
    } else if (b < nb0 + nbA) {
        dev_block_sum(needed, bsumA, b - nb0);
    } else {
        dev_block_sum(count1, bsumC, b - nb0 - nbA);
    }
}

// launch 4: scanA (writes nr_ptr) + scanC   (2 blocks)
__global__ __launch_bounds__(256) void scanAC_kernel(const int* __restrict__ bsumA,
                                                     int* __restrict__ boffA, int nbA,
                                                     int* __restrict__ nr_ptr,
                                                     const int* __restrict__ bsumC,
                                                     int* __restrict__ boffC, int nbC) {
    if (blockIdx.x == 0) dev_scan_small(bsumA, boffA, nbA, nr_ptr);
    else                 dev_scan_small(bsumC, boffC, nbC, nullptr);
}

// launch 5: finalA (rank) + finalC (csr1) + bsumB (count0)
__global__ __launch_bounds__(256) void finalAC_bsumB_kernel(const int* __restrict__ needed,
                                                            const int* __restrict__ boffA,
                                                            int* __restrict__ rank, int nbA,
                                                            const int* __restrict__ count1,
                                                            const int* __restrict__ boffC,
                                                            int* __restrict__ row_start1,
                                                            int* __restrict__ cursor1, int nbC,
                                                            const int* __restrict__ count0,
                                                            int* __restrict__ bsumB) {
    const int b = blockIdx.x;
    if (b < nbA)            dev_scan_final(needed, boffA, rank, rank, b);
    else if (b < nbA + nbC) dev_scan_final(count1, boffC, row_start1, cursor1, b - nbA);
    else                    dev_block_sum(count0, bsumB, b - nbA - nbC);
}

// launch 6: scanB (1 block)
__global__ __launch_bounds__(256) void scanB_kernel(const int* __restrict__ bsumB,
                                                    int* __restrict__ boffB, int nbB) {
    dev_scan_small(bsumB, boffB, nbB, nullptr);
}

// launch 7: finalB (csr0) + fill1 (needs rank + cursor1, both from launch 5)
__global__ __launch_bounds__(256) void finalB_fill1_kernel(const int* __restrict__ count0,
                                                           const int* __restrict__ boffB,
                                                           int* __restrict__ row_start0,
                                                           int* __restrict__ cursor0, int nbB,
                                                           const int* __restrict__ src1,
                                                           const int* __restrict__ dst1,
                                                           const int* __restrict__ rank,
                                                           int* __restrict__ cursor1,
                                                           int* __restrict__ edge_src1, int E1) {
    const int b = blockIdx.x;
    if (b < nbB) {
        dev_scan_final(count0, boffB, row_start0, cursor0, b);
    } else {                             // fill1 (identical to R3 fill w/ remap)
        int e = (b - nbB) * 256 + threadIdx.x;
        int d = dst1[e];
        int p = atomicAdd(&cursor1[d], 1);
        edge_src1[p] = rank[src1[e]];
    }
}

// launch 8: fill0 (needed-checked; needs cursor0 from launch 7)
__global__ __launch_bounds__(256) void fill0_kernel(const int* __restrict__ src0,
                                                    const int* __restrict__ dst0,
                                                    const int* __restrict__ needed,
                                                    int* __restrict__ cursor0,
                                                    int* __restrict__ edge_src0, int E0) {
    int e = blockIdx.x * 256 + threadIdx.x;
    int d = dst0[e];
    if (needed[d] == 0) return;
    int p = atomicAdd(&cursor0[d], 1);
    edge_src0[p] = src0[e];
}

// ---------------------------------------------------------------------------
// gather aggregation (VERBATIM R3): one wave per dst row; RF floats/lane.
template<int RF> struct VecSel;
template<> struct VecSel<2> { using V = float2; };
template<> struct VecSel<4> { using V = float4; };

template<int RF, bool COMPACT>
__global__ __launch_bounds__(256) void agg_kernel(const float* __restrict__ feat,
                                                  const float* __restrict__ selff,
                                                  const int* __restrict__ row_start,
                                                  const int* __restrict__ count,
                                                  const int* __restrict__ edge_src,
                                                  const int* __restrict__ needed,
                                                  const int* __restrict__ rank,
                                                  float* __restrict__ neigh,
                                                  float* __restrict__ deg, int ND) {
    using V = typename VecSel<RF>::V;
    int w = (blockIdx.x * 256 + threadIdx.x) >> 6;  // wave id == dst row
    int lane = threadIdx.x & 63;
    if (w >= ND) return;
    int out_r = w;
    if constexpr (COMPACT) {
        if (needed[w] == 0) return;
        out_r = rank[w];
    }
    const int K = 64 * RF;
    size_t lo_in  = (size_t)w * K + (size_t)lane * RF;
    size_t lo_out = (size_t)out_r * K + (size_t)lane * RF;
    V acc = *(const V*)(selff + lo_in);
    const int rs = row_start[w];
    const int cnt = count[w];

    for (int base = 0; base < cnt; base += 64) {
        const int rem = min(cnt - base, 64);
        const int idx = edge_src[rs + base + min(lane, rem - 1)];
        for (int jj = 0; jj < rem; jj += 8) {
            int s[8];
            float m[8];
            #pragma unroll
            for (int k = 0; k < 8; ++k) {
                int j = jj + k;
                s[k] = __shfl(idx, min(j, rem - 1));
                m[k] = (j < rem) ? 1.0f : 0.0f;
            }
            V v[8];
            #pragma unroll
            for (int k = 0; k < 8; ++k)
                v[k] = *(const V*)(feat + (size_t)s[k] * K + (size_t)lane * RF);
            #pragma unroll
            for (int k = 0; k < 8; ++k) {
                acc.x += v[k].x * m[k];
                acc.y += v[k].y * m[k];
                if constexpr (RF == 4) {
                    acc.z += v[k].z * m[k];
                    acc.w += v[k].w * m[k];
                }
            }
        }
    }
    *(V*)(neigh + lo_out) = acc;
    if (lane == 0) deg[out_r] = (float)(cnt + 1);
}

// ---------------------------------------------------------------------------
// GEMM (VERBATIM R3): C = act((A*rowscale)@W^T + b), 64x64x32, 4x4/thread.
template<bool RELU, bool HAS_RS, bool DYNM>
__global__ __launch_bounds__(256) void gemm_kernel(const float* __restrict__ A,    // M x K
                                                   const float* __restrict__ deg,  // M or null
                                                   const float* __restrict__ W,    // N x K
                                                   const float* __restrict__ bias, // N
                                                   float* __restrict__ C,          // M x N
                                                   const int* __restrict__ m_ptr,
                                                   int N, int K) {
    __shared__ float As[GEMM_BK][GEMM_BM];  // [k][m]
    __shared__ float Ws[GEMM_BK][GEMM_BN];  // [k][n]

    const int t = threadIdx.x;
    const int row0 = blockIdx.x * GEMM_BM;
    if constexpr (DYNM) {
        if (row0 >= *m_ptr) return;
    }
    const int col0 = blockIdx.y * GEMM_BN;

    const int tm = (t & 15) * 4;
    const int tn = (t >> 4) * 4;

    float acc[4][4] = {};

    const int lr = t >> 3;       // 0..31
    const int lk = (t & 7) * 4;  // 0,4,...,28

    for (int k0 = 0; k0 < K; k0 += GEMM_BK) {
        #pragma unroll
        for (int pass = 0; pass < 2; ++pass) {
            int r = lr + pass * 32;
            const float4 v = *(const float4*)(A + (size_t)(row0 + r) * K + k0 + lk);
            As[lk + 0][r] = v.x; As[lk + 1][r] = v.y;
            As[lk + 2][r] = v.z; As[lk + 3][r] = v.w;
        }
        #pragma unroll
        for (int pass = 0; pass < 2; ++pass) {
            int n = lr + pass * 32;
            const float4 v = *(const float4*)(W + (size_t)(col0 + n) * K + k0 + lk);
            Ws[lk + 0][n] = v.x; Ws[lk + 1][n] = v.y;
            Ws[lk + 2][n] = v.z; Ws[lk + 3][n] = v.w;
        }
        __syncthreads();

        #pragma unroll
        for (int k = 0; k < GEMM_BK; ++k) {
            const float4 a = *(const float4*)&As[k][tm];
            const float4 w = *(const float4*)&Ws[k][tn];
            acc[0][0] += a.x * w.x; acc[0][1] += a.x * w.y; acc[0][2] += a.x * w.z; acc[0][3] += a.x * w.w;
            acc[1][0] += a.y * w.x; acc[1][1] += a.y * w.y; acc[1][2] += a.y * w.z; acc[1][3] += a.y * w.w;
            acc[2][0] += a.z * w.x; acc[2][1] += a.z * w.y; acc[2][2] += a.z * w.z; acc[2][3] += a.z * w.w;
            acc[3][0] += a.w * w.x; acc[3][1] += a.w * w.y; acc[3][2] += a.w * w.z; acc[3][3] += a.w * w.w;
        }
        __syncthreads();
    }

    float scl[4];
    #pragma unroll
    for (int i = 0; i < 4; ++i)
        scl[i] = HAS_RS ? (1.0f / deg[row0 + tm + i]) : 1.0f;

    float bb[4];
    #pragma unroll
    for (int j = 0; j < 4; ++j) bb[j] = bias[col0 + tn + j];

    #pragma unroll
    for (int i = 0; i < 4; ++i) {
        float4 v;
        v.x = acc[i][0] * scl[i] + bb[0];
        v.y = acc[i][1] * scl[i] + bb[1];
        v.z = acc[i][2] * scl[i] + bb[2];
        v.w = acc[i][3] * scl[i] + bb[3];
        if (RELU) {
            v.x = fmaxf(v.x, 0.0f); v.y = fmaxf(v.y, 0.0f);
            v.z = fmaxf(v.z, 0.0f); v.w = fmaxf(v.w, 0.0f);
        }
        *(float4*)(C + (size_t)(row0 + tm + i) * N + col0 + tn) = v;
    }
}

// ---------------------------------------------------------------------------
extern "C" void kernel_launch(void* const* d_in, const int* in_sizes, int n_in,
                              void* d_out, int out_size, void* d_ws, size_t ws_size,
                              hipStream_t stream) {
    const float* x   = (const float*)d_in[0];
    const int* src0  = (const int*)d_in[1];
    const int* dst0  = (const int*)d_in[2];
    const int* src1  = (const int*)d_in[3];
    const int* dst1  = (const int*)d_in[4];
    const float* W1  = (const float*)d_in[5];
    const float* b1  = (const float*)d_in[6];
    const float* W2  = (const float*)d_in[7];
    const float* b2  = (const float*)d_in[8];
    const float* Wh  = (const float*)d_in[9];
    const float* bh  = (const float*)d_in[10];

    const int E0 = in_sizes[1];
    const int E1 = in_sizes[3];
    const int IN = 128, HID = 256, OUT = 256, PHEAD = 64;
    const int ND0 = 131072, ND1 = 8192;

    // ---- workspace layout (same as R3, + bsumC/boffC) ----
    float* ws = (float*)d_ws;
    float* neigh0c = ws;                               // ND0*IN (worst case)
    float* deg0c   = neigh0c + (size_t)ND0 * IN;       // ND0
    float* h1c     = deg0c + ND0;                      // ND0*HID (worst case)
    float* neigh1  = h1c + (size_t)ND0 * HID;          // ND1*HID
    float* deg1    = neigh1 + (size_t)ND1 * HID;       // ND1
    float* h2      = deg1 + ND1;                       // ND1*OUT
    float* out     = (float*)d_out;                    // ND1*PHEAD

    // count0, needed, count1 contiguous -> zeroed in ONE memset
    int* count0     = (int*)(h2 + (size_t)ND1 * OUT);  // ND0
    int* needed     = count0 + ND0;                    // ND0
    int* count1     = needed + ND0;                    // ND1
    int* rank       = count1 + ND1;                    // ND0
    int* row_start0 = rank + ND0;                      // ND0
    int* cursor0    = row_start0 + ND0;                // ND0
    int* edge_src0  = cursor0 + ND0;                   // E0
    int* row_start1 = edge_src0 + E0;                  // ND1
    int* cursor1    = row_start1 + ND1;                // ND1
    int* edge_src1  = cursor1 + ND1;                   // E1
    int* bsumA      = edge_src1 + E1;                  // 256
    int* boffA      = bsumA + 256;                     // 256
    int* bsumB      = boffA + 256;                     // 256
    int* boffB      = bsumB + 256;                     // 256
    int* bsumC      = boffB + 256;                     // 256
    int* boffC      = bsumC + 256;                     // 256
    int* nr_ptr     = boffC + 256;                     // 1: needed row count

    const int nbA = ND0 / 1024;  // 128 (needed scan)
    const int nbB = ND0 / 1024;  // 128 (count0 scan)
    const int nbC = ND1 / 1024;  // 8   (count1 scan)

    // 1. zero count0 + needed + count1
    hipMemsetAsync(count0, 0, (size_t)(2 * ND0 + ND1) * sizeof(int), stream);

    // 2. mark + hist1
    mark_hist1_kernel<<<2 * (E1 / 256), 256, 0, stream>>>(src1, needed, ND1,
                                                          dst1, count1, E1);

    // 3. hist0 (needed-checked) + bsumA + bsumC
    hist0_bsumAC_kernel<<<E0 / 256 + nbA + nbC, 256, 0, stream>>>(
        dst0, needed, count0, E0, bsumA, nbA, count1, bsumC);

    // 4. scanA (nr_ptr) + scanC
    scanAC_kernel<<<2, 256, 0, stream>>>(bsumA, boffA, nbA, nr_ptr, bsumC, boffC, nbC);

    // 5. finalA (rank) + finalC (csr1) + bsumB
    finalAC_bsumB_kernel<<<nbA + nbC + nbB, 256, 0, stream>>>(
        needed, boffA, rank, nbA, count1, boffC, row_start1, cursor1, nbC,
        count0, bsumB);

    // 6. scanB
    scanB_kernel<<<1, 256, 0, stream>>>(bsumB, boffB, nbB);

    // 7. finalB (csr0) + fill1 (rank-remapped)
    finalB_fill1_kernel<<<nbB + E1 / 256, 256, 0, stream>>>(
        count0, boffB, row_start0, cursor0, nbB,
        src1, dst1, rank, cursor1, edge_src1, E1);

    // 8. fill0 (needed-checked)
    fill0_kernel<<<E0 / 256, 256, 0, stream>>>(src0, dst0, needed, cursor0,
                                               edge_src0, E0);

    // 9. layer-0 gather aggregate (compacted out)
    agg_kernel<2, true><<<ND0 / 4, 256, 0, stream>>>(x, x, row_start0, count0, edge_src0,
                                                     needed, rank, neigh0c, deg0c, ND0);

    // 10. gemm1 (dynamic M = *nr_ptr)
    {
        dim3 g(ND0 / GEMM_BM, HID / GEMM_BN);
        gemm_kernel<true, true, true><<<g, 256, 0, stream>>>(neigh0c, deg0c, W1, b1, h1c,
                                                             nr_ptr, HID, IN);
    }

    // 11. layer-1 gather aggregate (edges pre-remapped; rank[d]=d for d<ND1)
    agg_kernel<4, false><<<ND1 / 4, 256, 0, stream>>>(h1c, h1c, row_start1, count1, edge_src1,
                                                      nullptr, nullptr, neigh1, deg1, ND1);

    // 12. gemm2
    {
        dim3 g(ND1 / GEMM_BM, OUT / GEMM_BN);
        gemm_kernel<true, true, false><<<g, 256, 0, stream>>>(neigh1, deg1, W2, b2, h2,
                                                              nullptr, OUT, HID);
    }

    // 13. head
    {
        dim3 g(ND1 / GEMM_BM, PHEAD / GEMM_BN);
        gemm_kernel<false, false, false><<<g, 256, 0, stream>>>(h2, nullptr, Wh, bh, out,
                                                                nullptr, PHEAD, OUT);
    }
}